// Round 1
// baseline (311.422 us; speedup 1.0000x reference)
//
#include <hip/hip_runtime.h>
#include <math.h>

#define NT   300
#define NA   3
#define BATCH 16
#define NCLS 80
#define CCH  85

// ws layout (doubles): [l*4+0]=lbox_sum  [l*4+1]=lcls_sum  [l*4+2]=obj_corr(Σ x*v)
//                      [l*4+3]=nvalid    [12+l]=obj softplus sum
// 15 doubles total; first 128 B of d_ws zeroed each launch.

__device__ __forceinline__ float softplusf(float x) {
    // matches max(x,0) + log1p(exp(-|x|))
    return fmaxf(x, 0.f) + log1pf(expf(-fabsf(x)));
}

__global__ __launch_bounds__(1024) void targets_kernel(
    const float* __restrict__ p0, const float* __restrict__ p1,
    const float* __restrict__ p2,
    const float* __restrict__ targets, const float* __restrict__ anchors,
    double* __restrict__ acc)
{
    const int li = blockIdx.x;                      // layer 0..2
    const float* p = (li == 0) ? p0 : ((li == 1) ? p1 : p2);
    const int W = 80 >> li;
    const int H = W;
    const int r = threadIdx.x;                      // row = a*NT + ti (tf order)

    __shared__ int    keys[1024];
    __shared__ double red[1024];

    float lbox = 0.f, lcls = 0.f, nval = 0.f, corr = 0.f;
    int   key = -1;
    float iou_clip = 0.f;
    float obj_x = 0.f;

    if (r < NA * NT) {
        const int a  = r / NT;
        const int ti = r - a * NT;
        const float img = targets[ti*6 + 0];
        const float cls = targets[ti*6 + 1];
        const float tx  = targets[ti*6 + 2] * (float)W;   // gain: x*W
        const float ty  = targets[ti*6 + 3] * (float)H;   // y*H
        const float tw  = targets[ti*6 + 4] * (float)W;   // w*W
        const float th  = targets[ti*6 + 5] * (float)H;   // h*H

        // wh-ratio mask vs layer anchors
        const float ax = anchors[(li*3 + a)*2 + 0];
        const float ay = anchors[(li*3 + a)*2 + 1];
        const float rx = tw / ax, ry = th / ay;
        const float mr = fmaxf(fmaxf(rx, 1.f/rx), fmaxf(ry, 1.f/ry));
        const bool  mask = mr < 4.f;
        const float mf = mask ? 1.f : 0.f;

        const int b = (int)img;
        const int c = (int)cls;
        const int gij_x = (int)tx;    // trunc, positive -> floor
        const int gij_y = (int)ty;
        const int gi = min(max(gij_x, 0), W - 1);
        const int gj = min(max(gij_y, 0), H - 1);

        // reference quirk: anch = anchors[a, a] (layer-independent)
        const float anch_x = anchors[(a*3 + a)*2 + 0];
        const float anch_y = anchors[(a*3 + a)*2 + 1];

        const int match = BATCH - 1 - b;
        const float* ps = p + ((((size_t)match*NA + a)*H + gj)*W + gi) * CCH;

        const float s0 = ps[0], s1 = ps[1], s2 = ps[2], s3 = ps[3];
        obj_x = ps[4];

        const float pxx = 1.f / (1.f + expf(-s0));
        const float pyy = 1.f / (1.f + expf(-s1));
        const float pw  = expf(s2) * anch_x;
        const float ph  = expf(s3) * anch_y;
        const float fx  = tx - (float)gij_x;
        const float fy  = ty - (float)gij_y;

        // CIoU(pbox=(pxx,pyy,pw,ph), tbox=(fx,fy,tw,th))
        const float eps = 1e-9f;
        const float b1x1 = pxx - pw*0.5f, b1x2 = pxx + pw*0.5f;
        const float b1y1 = pyy - ph*0.5f, b1y2 = pyy + ph*0.5f;
        const float b2x1 = fx - tw*0.5f,  b2x2 = fx + tw*0.5f;
        const float b2y1 = fy - th*0.5f,  b2y2 = fy + th*0.5f;
        float iw = fminf(b1x2, b2x2) - fmaxf(b1x1, b2x1); iw = fmaxf(iw, 0.f);
        float ih = fminf(b1y2, b2y2) - fmaxf(b1y1, b2y1); ih = fmaxf(ih, 0.f);
        const float inter = iw * ih;
        const float w1 = b1x2 - b1x1, h1 = b1y2 - b1y1 + eps;
        const float w2 = b2x2 - b2x1, h2 = b2y2 - b2y1 + eps;
        const float uni = w1*h1 + w2*h2 - inter + eps;
        const float iou = inter / uni;
        const float cw = fmaxf(b1x2, b2x2) - fminf(b1x1, b2x1);
        const float ch = fmaxf(b1y2, b2y2) - fminf(b1y1, b2y1);
        const float c2 = cw*cw + ch*ch + eps;
        const float dx = b2x1 + b2x2 - b1x1 - b1x2;
        const float dy = b2y1 + b2y2 - b1y1 - b1y2;
        const float rho2 = (dx*dx + dy*dy) * 0.25f;
        const float dat = atanf(w2/h2) - atanf(w1/h1);
        const float v = 0.40528473456935108577f * dat * dat;  // 4/pi^2
        const float alpha = v / (1.f + eps - iou + v);
        const float ciou = iou - (rho2/c2 + v*alpha);

        lbox = (1.f - ciou) * mf;
        nval = mf;

        // lcls row: sum_k bce(ps[5+k], onehot) = sum_k softplus - ps[5+c]
        float cls_sum = 0.f;
        #pragma unroll 8
        for (int k = 0; k < NCLS; ++k) cls_sum += softplusf(ps[5 + k]);
        cls_sum -= ps[5 + c];
        lcls = cls_sum * mf;

        if (mask) {
            key = ((match*NA + a)*H + gj)*W + gi;
            iou_clip = fmaxf(ciou, 0.f);
        }
    }

    keys[threadIdx.x] = key;
    __syncthreads();
    // last-wins dedup: row r is the scatter winner iff no later row shares its key
    if (key >= 0) {
        bool win = true;
        for (int j = threadIdx.x + 1; j < NA*NT; ++j)
            if (keys[j] == key) { win = false; break; }
        if (win) corr = obj_x * iou_clip;   // bce(x,t)-bce(x,0) = -x*t
    }

    // block reductions (one block per layer -> direct store, no atomics)
    double vals[4] = {(double)lbox, (double)lcls, (double)corr, (double)nval};
    for (int q = 0; q < 4; ++q) {
        red[threadIdx.x] = vals[q];
        __syncthreads();
        for (int s = 512; s > 0; s >>= 1) {
            if (threadIdx.x < s) red[threadIdx.x] += red[threadIdx.x + s];
            __syncthreads();
        }
        if (threadIdx.x == 0) acc[li*4 + q] = red[0];
        __syncthreads();
    }
}

// Sum softplus(preds[...,4]) over each layer's full grid.
// Blocks [0,300)->L0, [300,375)->L1, [375,394)->L2; 1024 elems/block.
__global__ __launch_bounds__(256) void obj_kernel(
    const float* __restrict__ p0, const float* __restrict__ p1,
    const float* __restrict__ p2, double* __restrict__ acc)
{
    const int blk = blockIdx.x;
    int li, bb;
    if (blk < 300)      { li = 0; bb = blk; }
    else if (blk < 375) { li = 1; bb = blk - 300; }
    else                { li = 2; bb = blk - 375; }
    const float* p = (li == 0) ? p0 : ((li == 1) ? p1 : p2);
    const int N = (BATCH * NA * 6400) >> (2*li);   // 307200 / 76800 / 19200

    const int base = bb*1024 + threadIdx.x;
    float s = 0.f;
    #pragma unroll
    for (int k = 0; k < 4; ++k) {
        const int idx = base + k*256;
        if (idx < N) s += softplusf(p[(size_t)idx * CCH + 4]);
    }

    __shared__ double red[256];
    red[threadIdx.x] = (double)s;
    __syncthreads();
    for (int st = 128; st > 0; st >>= 1) {
        if (threadIdx.x < st) red[threadIdx.x] += red[threadIdx.x + st];
        __syncthreads();
    }
    if (threadIdx.x == 0) atomicAdd(&acc[12 + li], red[0]);
}

__global__ void final_kernel(const double* __restrict__ acc,
                             float* __restrict__ out)
{
    double lbox = 0.0, lobj = 0.0, lcls = 0.0;
    for (int l = 0; l < 3; ++l) {
        const double nv = fmax(acc[l*4 + 3], 1.0);
        lbox += acc[l*4 + 0] / nv;
        lcls += acc[l*4 + 1] / (nv * (double)NCLS);
        const double N = (double)((BATCH * NA * 6400) >> (2*l));
        lobj += (acc[12 + l] - acc[l*4 + 2]) / N;
    }
    lbox *= 0.05;
    lcls *= 0.5;
    const double loss = lbox + lobj + lcls;
    out[0] = (float)loss;
    out[1] = (float)lbox;
    out[2] = (float)lobj;
    out[3] = (float)lcls;
    out[4] = (float)loss;
}

extern "C" void kernel_launch(void* const* d_in, const int* in_sizes, int n_in,
                              void* d_out, int out_size, void* d_ws, size_t ws_size,
                              hipStream_t stream) {
    const float* p0      = (const float*)d_in[0];
    const float* p1      = (const float*)d_in[1];
    const float* p2      = (const float*)d_in[2];
    const float* targets = (const float*)d_in[3];
    const float* anchors = (const float*)d_in[4];
    double* acc = (double*)d_ws;
    float*  out = (float*)d_out;

    hipMemsetAsync(d_ws, 0, 16 * sizeof(double), stream);
    targets_kernel<<<3, 1024, 0, stream>>>(p0, p1, p2, targets, anchors, acc);
    obj_kernel<<<394, 256, 0, stream>>>(p0, p1, p2, acc);
    final_kernel<<<1, 1, 0, stream>>>(acc, out);
}

// Round 2
// 227.017 us; speedup vs baseline: 1.3718x; 1.3718x over previous
//
#include <hip/hip_runtime.h>
#include <math.h>

#define NT    300
#define NA    3
#define BATCH 16
#define NCLS  80
#define CCH   85
#define NOB   99          // obj partial-sum blocks: 75 (L0) + 19 (L1) + 5 (L2)
#define HASHSZ 2048

// ws layout (doubles):
//   acc[l*4+0]=lbox_sum  acc[l*4+1]=lcls_sum  acc[l*4+2]=obj_corr  acc[l*4+3]=nvalid
//   acc[16+b] = obj softplus partial of block b (b in [0,NOB))
// Everything read by final_kernel is written unconditionally by main_kernel,
// so no memset of ws is needed.

__device__ __forceinline__ float softplusf(float x) {
    // == max(x,0) + log1p(exp(-|x|)) == bce(x, 0)
    return fmaxf(x, 0.f) + log1pf(expf(-fabsf(x)));
}

// full 1024-thread block reduce; result valid on thread 0
__device__ __forceinline__ double block_reduce(double v, double* red) {
    #pragma unroll
    for (int off = 32; off > 0; off >>= 1)
        v += __shfl_down(v, off, 64);
    const int wid  = threadIdx.x >> 6;
    const int lane = threadIdx.x & 63;
    if (lane == 0) red[wid] = v;
    __syncthreads();
    double r = (threadIdx.x < 16) ? red[threadIdx.x] : 0.0;
    #pragma unroll
    for (int off = 8; off > 0; off >>= 1)
        r += __shfl_down(r, off, 64);
    __syncthreads();   // red reusable after return
    return r;
}

__global__ __launch_bounds__(1024) void main_kernel(
    const float* __restrict__ p0, const float* __restrict__ p1,
    const float* __restrict__ p2,
    const float* __restrict__ targets, const float* __restrict__ anchors,
    double* __restrict__ acc)
{
    __shared__ double red[16];

    if (blockIdx.x < NOB) {
        // ---- obj softplus partial sums over preds[...,4] ----
        int li, bb;
        if (blockIdx.x < 75)      { li = 0; bb = blockIdx.x; }
        else if (blockIdx.x < 94) { li = 1; bb = blockIdx.x - 75; }
        else                      { li = 2; bb = blockIdx.x - 94; }
        const float* p = (li == 0) ? p0 : ((li == 1) ? p1 : p2);
        const int N = (BATCH * NA * 6400) >> (2*li);   // 307200/76800/19200

        const int base = bb * 4096 + threadIdx.x;
        float s = 0.f;
        #pragma unroll
        for (int k = 0; k < 4; ++k) {
            const int idx = base + k * 1024;
            if (idx < N) s += softplusf(p[(size_t)idx * CCH + 4]);
        }
        const double t = block_reduce((double)s, red);
        if (threadIdx.x == 0) acc[16 + blockIdx.x] = t;
        return;
    }

    // ---- per-target math, one block per layer ----
    __shared__ int tkey[HASHSZ];
    __shared__ int trow[HASHSZ];

    const int li = blockIdx.x - NOB;
    const float* p = (li == 0) ? p0 : ((li == 1) ? p1 : p2);
    const int W = 80 >> li;
    const int H = W;
    const int r = threadIdx.x;          // row = a*NT + ti (tf order)

    float lbox = 0.f, lcls = 0.f, nval = 0.f, corr = 0.f;
    int   key = -1, myslot = -1;
    float iou_clip = 0.f, obj_x = 0.f;

    if (r < NA * NT) {
        const int a  = r / NT;
        const int ti = r - a * NT;
        const float img = targets[ti*6 + 0];
        const float cls = targets[ti*6 + 1];
        const float tx  = targets[ti*6 + 2] * (float)W;
        const float ty  = targets[ti*6 + 3] * (float)H;
        const float tw  = targets[ti*6 + 4] * (float)W;
        const float th  = targets[ti*6 + 5] * (float)H;

        const float ax = anchors[(li*3 + a)*2 + 0];
        const float ay = anchors[(li*3 + a)*2 + 1];
        const float rx = tw / ax, ry = th / ay;
        const float mr = fmaxf(fmaxf(rx, 1.f/rx), fmaxf(ry, 1.f/ry));
        const bool  mask = mr < 4.f;
        const float mf = mask ? 1.f : 0.f;

        const int b = (int)img;
        const int c = (int)cls;
        const int gij_x = (int)tx;      // trunc == floor for positives
        const int gij_y = (int)ty;
        const int gi = min(max(gij_x, 0), W - 1);
        const int gj = min(max(gij_y, 0), H - 1);

        // reference quirk: anch = anchors[a, a] (layer-independent)
        const float anch_x = anchors[(a*3 + a)*2 + 0];
        const float anch_y = anchors[(a*3 + a)*2 + 1];

        const int match = BATCH - 1 - b;
        const float* ps = p + ((((size_t)match*NA + a)*H + gj)*W + gi) * CCH;

        const float s0 = ps[0], s1 = ps[1], s2 = ps[2], s3 = ps[3];
        obj_x = ps[4];

        const float pxx = 1.f / (1.f + expf(-s0));
        const float pyy = 1.f / (1.f + expf(-s1));
        const float pw  = expf(s2) * anch_x;
        const float ph  = expf(s3) * anch_y;
        const float fx  = tx - (float)gij_x;
        const float fy  = ty - (float)gij_y;

        const float eps = 1e-9f;
        const float b1x1 = pxx - pw*0.5f, b1x2 = pxx + pw*0.5f;
        const float b1y1 = pyy - ph*0.5f, b1y2 = pyy + ph*0.5f;
        const float b2x1 = fx - tw*0.5f,  b2x2 = fx + tw*0.5f;
        const float b2y1 = fy - th*0.5f,  b2y2 = fy + th*0.5f;
        float iw = fminf(b1x2, b2x2) - fmaxf(b1x1, b2x1); iw = fmaxf(iw, 0.f);
        float ih = fminf(b1y2, b2y2) - fmaxf(b1y1, b2y1); ih = fmaxf(ih, 0.f);
        const float inter = iw * ih;
        const float w1 = b1x2 - b1x1, h1 = b1y2 - b1y1 + eps;
        const float w2 = b2x2 - b2x1, h2 = b2y2 - b2y1 + eps;
        const float uni = w1*h1 + w2*h2 - inter + eps;
        const float iou = inter / uni;
        const float cw = fmaxf(b1x2, b2x2) - fminf(b1x1, b2x1);
        const float ch = fmaxf(b1y2, b2y2) - fminf(b1y1, b2y1);
        const float c2 = cw*cw + ch*ch + eps;
        const float dx = b2x1 + b2x2 - b1x1 - b1x2;
        const float dy = b2y1 + b2y2 - b1y1 - b1y2;
        const float rho2 = (dx*dx + dy*dy) * 0.25f;
        const float dat = atanf(w2/h2) - atanf(w1/h1);
        const float v = 0.40528473456935108577f * dat * dat;  // 4/pi^2
        const float alpha = v / (1.f + eps - iou + v);
        const float ciou = iou - (rho2/c2 + v*alpha);

        lbox = (1.f - ciou) * mf;
        nval = mf;

        float cls_sum = 0.f;
        #pragma unroll 20
        for (int k = 0; k < NCLS; ++k) cls_sum += softplusf(ps[5 + k]);
        cls_sum -= ps[5 + c];
        lcls = cls_sum * mf;

        if (mask) {
            key = ((match*NA + a)*H + gj)*W + gi;
            iou_clip = fmaxf(ciou, 0.f);
        }
    }

    // ---- last-wins scatter dedup via LDS hash (key -> max row) ----
    tkey[threadIdx.x]        = -1;
    tkey[threadIdx.x + 1024] = -1;
    trow[threadIdx.x]        = -1;
    trow[threadIdx.x + 1024] = -1;
    __syncthreads();

    if (key >= 0) {
        unsigned h = ((unsigned)key * 2654435761u) >> 21;
        int s = (int)(h & (HASHSZ - 1));
        while (true) {
            const int prev = atomicCAS(&tkey[s], -1, key);
            if (prev == -1 || prev == key) {
                atomicMax(&trow[s], r);
                myslot = s;
                break;
            }
            s = (s + 1) & (HASHSZ - 1);
        }
    }
    __syncthreads();
    if (key >= 0 && trow[myslot] == r)
        corr = obj_x * iou_clip;        // bce(x,t) - bce(x,0) = -x*t

    const double vb = block_reduce((double)lbox, red);
    const double vc = block_reduce((double)lcls, red);
    const double vo = block_reduce((double)corr, red);
    const double vn = block_reduce((double)nval, red);
    if (threadIdx.x == 0) {
        acc[li*4 + 0] = vb;
        acc[li*4 + 1] = vc;
        acc[li*4 + 2] = vo;
        acc[li*4 + 3] = vn;
    }
}

__global__ __launch_bounds__(64) void final_kernel(
    const double* __restrict__ acc, float* __restrict__ out)
{
    double s0 = 0.0, s1 = 0.0, s2 = 0.0;
    for (int b = threadIdx.x; b < NOB; b += 64) {
        const double v = acc[16 + b];
        if (b < 75)      s0 += v;
        else if (b < 94) s1 += v;
        else             s2 += v;
    }
    #pragma unroll
    for (int off = 32; off > 0; off >>= 1) {
        s0 += __shfl_down(s0, off, 64);
        s1 += __shfl_down(s1, off, 64);
        s2 += __shfl_down(s2, off, 64);
    }
    if (threadIdx.x == 0) {
        const double os[3] = {s0, s1, s2};
        double lbox = 0.0, lobj = 0.0, lcls = 0.0;
        for (int l = 0; l < 3; ++l) {
            const double nv = fmax(acc[l*4 + 3], 1.0);
            lbox += acc[l*4 + 0] / nv;
            lcls += acc[l*4 + 1] / (nv * (double)NCLS);
            const double N = (double)((BATCH * NA * 6400) >> (2*l));
            lobj += (os[l] - acc[l*4 + 2]) / N;
        }
        lbox *= 0.05;
        lcls *= 0.5;
        const double loss = lbox + lobj + lcls;
        out[0] = (float)loss;
        out[1] = (float)lbox;
        out[2] = (float)lobj;
        out[3] = (float)lcls;
        out[4] = (float)loss;
    }
}

extern "C" void kernel_launch(void* const* d_in, const int* in_sizes, int n_in,
                              void* d_out, int out_size, void* d_ws, size_t ws_size,
                              hipStream_t stream) {
    const float* p0      = (const float*)d_in[0];
    const float* p1      = (const float*)d_in[1];
    const float* p2      = (const float*)d_in[2];
    const float* targets = (const float*)d_in[3];
    const float* anchors = (const float*)d_in[4];
    double* acc = (double*)d_ws;
    float*  out = (float*)d_out;

    main_kernel<<<NOB + 3, 1024, 0, stream>>>(p0, p1, p2, targets, anchors, acc);
    final_kernel<<<1, 64, 0, stream>>>(acc, out);
}